// Round 11
// baseline (766.178 us; speedup 1.0000x reference)
//
#include <hip/hip_runtime.h>
#include <hip/hip_bf16.h>

// Chamfer loss via 32x32x16 MFMA — 3 dispatches, occupancy-first.
// predict_pc [B=4,3,N=8192] f32, gt_pc [B,3,N] f32.
// loss = sum_gt min_pred d / B + sum_pred min_gt d / B
//
// m := d^2/2 = on + qn - o.q via bf16 MFMA 32x32x16, split-bf16 (hi+lo ~fp32).
// Records (16 shorts, bit-identical to R6/R7/R10-validated):
//   A (opposite): [-oh(3), -oh(3), -ol(3), -ol(3), onh, onl, 1, 1]
//   B (query):    [ qh(3),  ql(3),  qh(3),  ql(3), 1, 1, qnh, qnl]
// Geometry (R10 post-mortem: 1 block/CU = latency-bound, occupancy 9.9%):
// grid = 2*4*qtiles*ncs = 1024 blocks -> 4 blocks/CU = 4 waves/SIMD.
// Each block: 512 queries (4 waves x 4 frags x 32 cols), scans a 1024-point
// opposite strip (ncs=8) via double-buffered LDS chunks (OC=256, ONE barrier
// per chunk, scalar-float prefetch before compute, pack after — R10-proven).
// q-records stage into the SAME LDS as the o-buffers (dead after bfrag
// loads) -> 24 KB LDS, so LDS never caps occupancy.
// Output: strip-partial mins [2*4*ncs][N]; reduce1 min-merges + sqrt +
// block-sums (256 blocks); reduce2 sums 256 partials. No atomics, no memset.

#define NQ 512      // queries per block (4 waves x 128 cols)
#define OC 256      // opposite points per LDS chunk
#define LDR 24      // record stride in shorts (16 + 8 pad = 48 B)
#define JF 4        // B-frags per wave
#define NCS 8       // opposite-strip split count
#define RBLKS 256

typedef short short8 __attribute__((ext_vector_type(8)));
typedef float f32x16 __attribute__((ext_vector_type(16)));

static __device__ inline unsigned short f2bf(float f) {
    __hip_bfloat16 h = __float2bfloat16(f);
    return *reinterpret_cast<unsigned short*>(&h);
}
static __device__ inline float bf2f(unsigned short u) {
    __hip_bfloat16 h;
    *reinterpret_cast<unsigned short*>(&h) = u;
    return __bfloat162float(h);
}
static __device__ inline void split_bf(float v, unsigned short& hi,
                                       unsigned short& lo) {
    hi = f2bf(v);
    lo = f2bf(v - bf2f(hi));
}
static __device__ inline float min3f(float a, float b, float c) {
    return fminf(fminf(a, b), c);   // clang fuses to v_min3_f32
}

// A-side record (negated coords), proven content
static __device__ inline void pack_A(unsigned short* dst,
                                     float x, float y, float z) {
    unsigned short hx, lx, hy, ly, hz, lz, nh, nl;
    split_bf(x, hx, lx); split_bf(y, hy, ly); split_bf(z, hz, lz);
    float on = 0.5f * fmaf(x, x, fmaf(y, y, z * z));
    split_bf(on, nh, nl);
    const unsigned short ONE = 0x3F80;
    __align__(16) unsigned short r[16] = {
        (unsigned short)(hx ^ 0x8000), (unsigned short)(hy ^ 0x8000),
        (unsigned short)(hz ^ 0x8000), (unsigned short)(hx ^ 0x8000),
        (unsigned short)(hy ^ 0x8000), (unsigned short)(hz ^ 0x8000),
        (unsigned short)(lx ^ 0x8000), (unsigned short)(ly ^ 0x8000),
        (unsigned short)(lz ^ 0x8000), (unsigned short)(lx ^ 0x8000),
        (unsigned short)(ly ^ 0x8000), (unsigned short)(lz ^ 0x8000),
        nh, nl, ONE, ONE};
    *(short8*)(dst + 0) = ((const short8*)r)[0];
    *(short8*)(dst + 8) = ((const short8*)r)[1];
}

__global__ __launch_bounds__(256, 4) void chamfer_mfma_kernel(
    const float* __restrict__ pred, const float* __restrict__ gt,
    float* __restrict__ partial,   // [(dir*4+b)*NCS+cs][N]
    int N, int qtiles, int nchunks)
{
    // o_lds double buffer; q-records alias the same storage (dead after
    // bfrag loads). 2 x 256 x 24 shorts = 24 KB total.
    __align__(16) __shared__ unsigned short o_lds[2][OC * LDR];
    unsigned short* q_lds = &o_lds[0][0];   // 512 recs = exactly 24 KB

    int bid = blockIdx.x;
    int cs = bid % NCS;   int t1 = bid / NCS;
    int qt = t1 % qtiles; int t2 = t1 / qtiles;
    int b  = t2 & 3;      int dir = t2 >> 2;

    const float* qpts = dir ? pred : gt;   // dir0: queries=gt (z)
    const float* opts = dir ? gt   : pred; // dir1: queries=pred (z2)
    const float* qb = qpts + (size_t)b * 3 * N;
    const float* ob = opts + (size_t)b * 3 * N;

    int tid = threadIdx.x;
    int lane = tid & 63, w = tid >> 6;
    int col = lane & 31, h = lane >> 5;
    const unsigned short ONE = 0x3F80;

    // ---- stage this block's 512 query records into (aliased) LDS ----
    #pragma unroll
    for (int s = 0; s < 2; ++s) {
        int sq = tid + s * 256;
        int qi = qt * NQ + sq;
        float x = qb[qi], y = qb[N + qi], z = qb[2 * N + qi];
        unsigned short hx, lx, hy, ly, hz, lz, nh, nl;
        split_bf(x, hx, lx); split_bf(y, hy, ly); split_bf(z, hz, lz);
        float qn = 0.5f * fmaf(x, x, fmaf(y, y, z * z));
        split_bf(qn, nh, nl);
        __align__(16) unsigned short r[16] = {
            hx, hy, hz, lx, ly, lz, hx, hy, hz, lx, ly, lz, ONE, ONE, nh, nl};
        unsigned short* dst = q_lds + sq * LDR;
        *(short8*)(dst + 0) = ((const short8*)r)[0];
        *(short8*)(dst + 8) = ((const short8*)r)[1];
    }
    __syncthreads();

    // B-frags: this wave's 128 query columns, registers for whole kernel
    short8 bfrag[JF];
    #pragma unroll
    for (int j = 0; j < JF; ++j)
        bfrag[j] = *(const short8*)(q_lds + (w * 128 + j * 32 + col) * LDR + h * 8);
    __syncthreads();   // all bfrag reads done before o-staging overwrites

    int obase = cs * (nchunks * OC);
    {   // prologue: stage opposite chunk 0 into buf0
        int oi = obase + tid;
        pack_A(&o_lds[0][0] + tid * LDR, ob[oi], ob[N + oi], ob[2 * N + oi]);
    }
    __syncthreads();

    float mn[JF] = {3.0e38f, 3.0e38f, 3.0e38f, 3.0e38f};
    const f32x16 zero16 = {0.f};

    for (int c = 0; c < nchunks; ++c) {
        int cur = c & 1;
        bool pf = (c + 1 < nchunks);
        float px = 0.f, py = 0.f, pz = 0.f;
        if (pf) {   // prefetch next chunk's floats (hides HBM/L2 latency)
            int oi = obase + (c + 1) * OC + tid;
            px = ob[oi]; py = ob[N + oi]; pz = ob[2 * N + oi];
        }

        const unsigned short* ol = &o_lds[cur][0];
        #pragma unroll
        for (int i = 0; i < OC / 32; ++i) {
            short8 af = *(const short8*)(ol + (i * 32 + col) * LDR + h * 8);
            #pragma unroll
            for (int j = 0; j < JF; ++j) {
                f32x16 acc = __builtin_amdgcn_mfma_f32_32x32x16_bf16(
                    af, bfrag[j], zero16, 0, 0, 0);
                float l0 = min3f(acc[0],  acc[1],  acc[2]);
                float l1 = min3f(acc[3],  acc[4],  acc[5]);
                float l2 = min3f(acc[6],  acc[7],  acc[8]);
                float l3 = min3f(acc[9],  acc[10], acc[11]);
                float l4 = min3f(acc[12], acc[13], acc[14]);
                float m0 = min3f(l0, l1, l2);
                float m1 = min3f(l3, l4, acc[15]);
                mn[j] = min3f(m0, m1, mn[j]);
            }
        }

        if (pf) pack_A(&o_lds[cur ^ 1][0] + tid * LDR, px, py, pz);
        __syncthreads();
    }

    // fold the two k-half lane groups (rows +4h) of each query column
    #pragma unroll
    for (int j = 0; j < JF; ++j)
        mn[j] = fminf(mn[j], __shfl_xor(mn[j], 32, 64));

    if (lane < 32) {
        float* pp = partial + ((size_t)((dir * 4 + b) * NCS + cs)) * N
                  + qt * NQ + w * 128 + col;
        #pragma unroll
        for (int j = 0; j < JF; ++j) pp[j * 32] = mn[j];
    }
}

__global__ __launch_bounds__(256) void chamfer_reduce1_kernel(
    const float* __restrict__ partial, float* __restrict__ partials2, int N)
{
    __shared__ float sdata[256];
    int L = blockIdx.x * 256 + threadIdx.x;   // over 2*B*N queries
    int dirb = L / N, q = L - dirb * N;
    const float* pp = partial + (size_t)dirb * NCS * N + q;
    float v = pp[0];
    #pragma unroll
    for (int cs = 1; cs < NCS; ++cs) v = fminf(v, pp[(size_t)cs * N]);
    float s = sqrtf(fmaxf(2.0f * v, 0.0f));   // d = sqrt(2m)
    sdata[threadIdx.x] = s;
    __syncthreads();
    for (int off = 128; off > 0; off >>= 1) {
        if (threadIdx.x < off) sdata[threadIdx.x] += sdata[threadIdx.x + off];
        __syncthreads();
    }
    if (threadIdx.x == 0) partials2[blockIdx.x] = sdata[0];
}

__global__ __launch_bounds__(256) void chamfer_reduce2_kernel(
    const float* __restrict__ partials2, float* __restrict__ out, float inv_b)
{
    __shared__ float sdata[256];
    sdata[threadIdx.x] = partials2[threadIdx.x];
    __syncthreads();
    for (int off = 128; off > 0; off >>= 1) {
        if (threadIdx.x < off) sdata[threadIdx.x] += sdata[threadIdx.x + off];
        __syncthreads();
    }
    if (threadIdx.x == 0) out[0] = sdata[0] * inv_b;
}

extern "C" void kernel_launch(void* const* d_in, const int* in_sizes, int n_in,
                              void* d_out, int out_size, void* d_ws, size_t ws_size,
                              hipStream_t stream) {
    const float* pred = (const float*)d_in[0];
    const float* gt   = (const float*)d_in[1];
    const int B = 4, D = 3;
    const int N = in_sizes[0] / (B * D);   // 8192

    float* partial   = (float*)d_ws;                        // [2*B*NCS][N] = 2 MB
    float* partials2 = partial + (size_t)2 * B * NCS * N;   // [RBLKS]

    int qtiles  = N / NQ;              // 16
    int strip   = N / NCS;             // 1024
    int nchunks = strip / OC;          // 4
    dim3 grid1(2 * B * qtiles * NCS);  // 1024 blocks -> 4/CU
    chamfer_mfma_kernel<<<grid1, dim3(256), 0, stream>>>(
        pred, gt, partial, N, qtiles, nchunks);

    chamfer_reduce1_kernel<<<dim3(2 * B * N / 256), dim3(256), 0, stream>>>(
        partial, partials2, N);
    chamfer_reduce2_kernel<<<dim3(1), dim3(256), 0, stream>>>(
        partials2, (float*)d_out, 1.0f / B);
}

// Round 12
// 36.393 us; speedup vs baseline: 21.0527x; 21.0527x over previous
//
#include <hip/hip_runtime.h>
#include <hip/hip_bf16.h>

// Chamfer loss via 32x32x16 MFMA — R10-proven kernel body x R11 strip grid.
// predict_pc [B=4,3,N=8192] f32, gt_pc [B,3,N] f32.
// loss = sum_gt min_pred d / B + sum_pred min_gt d / B
//
// m := d^2/2 = on + qn - o.q via bf16 MFMA 32x32x16, split-bf16 (hi+lo ~fp32).
// Records (16 shorts, bit-identical to R6/R7/R10-validated):
//   A (opposite): [-oh(3), -oh(3), -ol(3), -ol(3), onh, onl, 1, 1]
//   B (query):    [ qh(3),  ql(3),  qh(3),  ql(3), 1, 1, qnh, qnl]
// LESSON (R8/R11): __launch_bounds__(256,4) + this loop spills (64 VGPR cap,
// 1.8 GB scratch writes). Use plain __launch_bounds__(256) — R10 got 88 VGPR,
// no spill. Occupancy comes from the grid: 2048 blocks (~8/CU submitted).
// Block: 256 queries (4 waves x 2 frags x 32 cols) x 1024-pt opposite strip
// (NCS=8) via double-buffered LDS chunks (OC=256, one barrier per chunk,
// scalar-float prefetch before compute, pack_A after — R10-proven).
// Output: strip-partial mins [2*4*NCS][N]; reduce1 min-merges + sqrt +
// block-sums; reduce2 sums. No atomics, no memset, deterministic.

#define NQ 256      // queries per block
#define OC 256      // opposite points per LDS chunk
#define LDR 24      // record stride in shorts (16 + 8 pad = 48 B)
#define JF 2        // B-frags per wave
#define NCS 8       // opposite-strip split count

typedef short short8 __attribute__((ext_vector_type(8)));
typedef float f32x16 __attribute__((ext_vector_type(16)));

static __device__ inline unsigned short f2bf(float f) {
    __hip_bfloat16 h = __float2bfloat16(f);
    return *reinterpret_cast<unsigned short*>(&h);
}
static __device__ inline float bf2f(unsigned short u) {
    __hip_bfloat16 h;
    *reinterpret_cast<unsigned short*>(&h) = u;
    return __bfloat162float(h);
}
static __device__ inline void split_bf(float v, unsigned short& hi,
                                       unsigned short& lo) {
    hi = f2bf(v);
    lo = f2bf(v - bf2f(hi));
}
static __device__ inline float min3f(float a, float b, float c) {
    return fminf(fminf(a, b), c);   // clang fuses to v_min3_f32
}

// A-side record (negated coords), proven content
static __device__ inline void pack_A(unsigned short* dst,
                                     float x, float y, float z) {
    unsigned short hx, lx, hy, ly, hz, lz, nh, nl;
    split_bf(x, hx, lx); split_bf(y, hy, ly); split_bf(z, hz, lz);
    float on = 0.5f * fmaf(x, x, fmaf(y, y, z * z));
    split_bf(on, nh, nl);
    const unsigned short ONE = 0x3F80;
    __align__(16) unsigned short r[16] = {
        (unsigned short)(hx ^ 0x8000), (unsigned short)(hy ^ 0x8000),
        (unsigned short)(hz ^ 0x8000), (unsigned short)(hx ^ 0x8000),
        (unsigned short)(hy ^ 0x8000), (unsigned short)(hz ^ 0x8000),
        (unsigned short)(lx ^ 0x8000), (unsigned short)(ly ^ 0x8000),
        (unsigned short)(lz ^ 0x8000), (unsigned short)(lx ^ 0x8000),
        (unsigned short)(ly ^ 0x8000), (unsigned short)(lz ^ 0x8000),
        nh, nl, ONE, ONE};
    *(short8*)(dst + 0) = ((const short8*)r)[0];
    *(short8*)(dst + 8) = ((const short8*)r)[1];
}

__global__ __launch_bounds__(256) void chamfer_mfma_kernel(
    const float* __restrict__ pred, const float* __restrict__ gt,
    float* __restrict__ partial,   // [(dir*4+b)*NCS+cs][N]
    int N, int qtiles, int nchunks)
{
    __align__(16) __shared__ unsigned short q_lds[NQ * LDR];      // 12 KB
    __align__(16) __shared__ unsigned short o_lds[2][OC * LDR];   // 24 KB

    int bid = blockIdx.x;
    int cs = bid % NCS;   int t1 = bid / NCS;
    int qt = t1 % qtiles; int t2 = t1 / qtiles;
    int b  = t2 & 3;      int dir = t2 >> 2;

    const float* qpts = dir ? pred : gt;   // dir0: queries=gt (z)
    const float* opts = dir ? gt   : pred; // dir1: queries=pred (z2)
    const float* qb = qpts + (size_t)b * 3 * N;
    const float* ob = opts + (size_t)b * 3 * N;

    int tid = threadIdx.x;
    int lane = tid & 63, w = tid >> 6;
    int col = lane & 31, h = lane >> 5;
    const unsigned short ONE = 0x3F80;

    // ---- stage this block's 256 query records (B-side) ----
    {
        int qi = qt * NQ + tid;
        float x = qb[qi], y = qb[N + qi], z = qb[2 * N + qi];
        unsigned short hx, lx, hy, ly, hz, lz, nh, nl;
        split_bf(x, hx, lx); split_bf(y, hy, ly); split_bf(z, hz, lz);
        float qn = 0.5f * fmaf(x, x, fmaf(y, y, z * z));
        split_bf(qn, nh, nl);
        __align__(16) unsigned short r[16] = {
            hx, hy, hz, lx, ly, lz, hx, hy, hz, lx, ly, lz, ONE, ONE, nh, nl};
        unsigned short* dst = q_lds + tid * LDR;
        *(short8*)(dst + 0) = ((const short8*)r)[0];
        *(short8*)(dst + 8) = ((const short8*)r)[1];
    }
    // ---- prologue: stage opposite chunk 0 ----
    int obase = cs * (nchunks * OC);
    {
        int oi = obase + tid;
        pack_A(&o_lds[0][0] + tid * LDR, ob[oi], ob[N + oi], ob[2 * N + oi]);
    }
    __syncthreads();

    // B-frags: this wave's 64 query columns, registers for whole kernel
    short8 bfrag[JF];
    #pragma unroll
    for (int j = 0; j < JF; ++j)
        bfrag[j] = *(const short8*)(q_lds + (w * 64 + j * 32 + col) * LDR + h * 8);

    float mn[JF] = {3.0e38f, 3.0e38f};
    const f32x16 zero16 = {0.f};

    for (int c = 0; c < nchunks; ++c) {
        int cur = c & 1;
        bool pf = (c + 1 < nchunks);
        float px = 0.f, py = 0.f, pz = 0.f;
        if (pf) {   // prefetch next chunk's floats (hides HBM/L2 latency)
            int oi = obase + (c + 1) * OC + tid;
            px = ob[oi]; py = ob[N + oi]; pz = ob[2 * N + oi];
        }

        const unsigned short* ol = &o_lds[cur][0];
        #pragma unroll 4
        for (int i = 0; i < OC / 32; ++i) {
            short8 af = *(const short8*)(ol + (i * 32 + col) * LDR + h * 8);
            #pragma unroll
            for (int j = 0; j < JF; ++j) {
                f32x16 acc = __builtin_amdgcn_mfma_f32_32x32x16_bf16(
                    af, bfrag[j], zero16, 0, 0, 0);
                float l0 = min3f(acc[0],  acc[1],  acc[2]);
                float l1 = min3f(acc[3],  acc[4],  acc[5]);
                float l2 = min3f(acc[6],  acc[7],  acc[8]);
                float l3 = min3f(acc[9],  acc[10], acc[11]);
                float l4 = min3f(acc[12], acc[13], acc[14]);
                float m0 = min3f(l0, l1, l2);
                float m1 = min3f(l3, l4, acc[15]);
                mn[j] = min3f(m0, m1, mn[j]);
            }
        }

        if (pf) pack_A(&o_lds[cur ^ 1][0] + tid * LDR, px, py, pz);
        __syncthreads();
    }

    // fold the two k-half lane groups (rows +4h) of each query column
    #pragma unroll
    for (int j = 0; j < JF; ++j)
        mn[j] = fminf(mn[j], __shfl_xor(mn[j], 32, 64));

    if (lane < 32) {
        float* pp = partial + ((size_t)((dir * 4 + b) * NCS + cs)) * N
                  + qt * NQ + w * 64 + col;
        #pragma unroll
        for (int j = 0; j < JF; ++j) pp[j * 32] = mn[j];
    }
}

__global__ __launch_bounds__(256) void chamfer_reduce1_kernel(
    const float* __restrict__ partial, float* __restrict__ partials2, int N)
{
    __shared__ float sdata[256];
    int L = blockIdx.x * 256 + threadIdx.x;   // over 2*B*N queries
    int dirb = L / N, q = L - dirb * N;
    const float* pp = partial + (size_t)dirb * NCS * N + q;
    float v = pp[0];
    #pragma unroll
    for (int cs = 1; cs < NCS; ++cs) v = fminf(v, pp[(size_t)cs * N]);
    float s = sqrtf(fmaxf(2.0f * v, 0.0f));   // d = sqrt(2m)
    sdata[threadIdx.x] = s;
    __syncthreads();
    for (int off = 128; off > 0; off >>= 1) {
        if (threadIdx.x < off) sdata[threadIdx.x] += sdata[threadIdx.x + off];
        __syncthreads();
    }
    if (threadIdx.x == 0) partials2[blockIdx.x] = sdata[0];
}

__global__ __launch_bounds__(256) void chamfer_reduce2_kernel(
    const float* __restrict__ partials2, float* __restrict__ out, float inv_b)
{
    __shared__ float sdata[256];
    sdata[threadIdx.x] = partials2[threadIdx.x];
    __syncthreads();
    for (int off = 128; off > 0; off >>= 1) {
        if (threadIdx.x < off) sdata[threadIdx.x] += sdata[threadIdx.x + off];
        __syncthreads();
    }
    if (threadIdx.x == 0) out[0] = sdata[0] * inv_b;
}

extern "C" void kernel_launch(void* const* d_in, const int* in_sizes, int n_in,
                              void* d_out, int out_size, void* d_ws, size_t ws_size,
                              hipStream_t stream) {
    const float* pred = (const float*)d_in[0];
    const float* gt   = (const float*)d_in[1];
    const int B = 4, D = 3;
    const int N = in_sizes[0] / (B * D);   // 8192

    float* partial   = (float*)d_ws;                        // [2*B*NCS][N] = 2 MB
    float* partials2 = partial + (size_t)2 * B * NCS * N;   // [256]

    int qtiles  = N / NQ;              // 32
    int strip   = N / NCS;             // 1024
    int nchunks = strip / OC;          // 4
    dim3 grid1(2 * B * qtiles * NCS);  // 2048 blocks
    chamfer_mfma_kernel<<<grid1, dim3(256), 0, stream>>>(
        pred, gt, partial, N, qtiles, nchunks);

    chamfer_reduce1_kernel<<<dim3(2 * B * N / 256), dim3(256), 0, stream>>>(
        partial, partials2, N);
    chamfer_reduce2_kernel<<<dim3(1), dim3(256), 0, stream>>>(
        partials2, (float*)d_out, 1.0f / B);
}